// Round 8
// baseline (83.564 us; speedup 1.0000x reference)
//
#include <hip/hip_runtime.h>
#include <hip/hip_bf16.h>
#include <math.h>

typedef __attribute__((ext_vector_type(8))) short short8;
typedef __attribute__((ext_vector_type(4))) float f32x4;
typedef unsigned int uint;
typedef unsigned short ushort;

#define HWSZ 16384
#define PADW 130
#define SLAB (PADW*PADW*64)
// window: 11 rows x 23 cols of 128B cells, origin (i0-2, j0-2) padded coords
#define WR 11
#define WC 23
#define NCELL (WR*WC)            // 253
#define OMS_OFF 32384            // bytes: 253*128
#define SM_BYTES (32384 + 4*27*17*4)

__device__ __forceinline__ uint pk2bf(float a, float b) {
    union { __hip_bfloat162 h; uint u; } cv;
    cv.h = __float22bfloat162_rn(make_float2(a, b)); return cv.u;
}
__device__ __forceinline__ float bflo(uint u){ return __uint_as_float(u << 16); }
__device__ __forceinline__ float bfhi(uint u){ return __uint_as_float(u & 0xffff0000u); }

__device__ __forceinline__ short8 combine4(short8 s0, short8 s1, short8 s2, short8 s3,
                                           float g0, float g1, float g2, float g3)
{
    uint4 u0 = *(uint4*)&s0, u1 = *(uint4*)&s1, u2 = *(uint4*)&s2, u3 = *(uint4*)&s3;
    float v0,v1,v2,v3,v4,v5,v6,v7;
    v0 = g0*bflo(u0.x); v1 = g0*bfhi(u0.x); v2 = g0*bflo(u0.y); v3 = g0*bfhi(u0.y);
    v4 = g0*bflo(u0.z); v5 = g0*bfhi(u0.z); v6 = g0*bflo(u0.w); v7 = g0*bfhi(u0.w);
    v0 = fmaf(g1,bflo(u1.x),v0); v1 = fmaf(g1,bfhi(u1.x),v1);
    v2 = fmaf(g1,bflo(u1.y),v2); v3 = fmaf(g1,bfhi(u1.y),v3);
    v4 = fmaf(g1,bflo(u1.z),v4); v5 = fmaf(g1,bfhi(u1.z),v5);
    v6 = fmaf(g1,bflo(u1.w),v6); v7 = fmaf(g1,bfhi(u1.w),v7);
    v0 = fmaf(g2,bflo(u2.x),v0); v1 = fmaf(g2,bfhi(u2.x),v1);
    v2 = fmaf(g2,bflo(u2.y),v2); v3 = fmaf(g2,bfhi(u2.y),v3);
    v4 = fmaf(g2,bflo(u2.z),v4); v5 = fmaf(g2,bfhi(u2.z),v5);
    v6 = fmaf(g2,bflo(u2.w),v6); v7 = fmaf(g2,bfhi(u2.w),v7);
    v0 = fmaf(g3,bflo(u3.x),v0); v1 = fmaf(g3,bfhi(u3.x),v1);
    v2 = fmaf(g3,bflo(u3.y),v2); v3 = fmaf(g3,bfhi(u3.y),v3);
    v4 = fmaf(g3,bflo(u3.z),v4); v5 = fmaf(g3,bfhi(u3.z),v5);
    v6 = fmaf(g3,bflo(u3.w),v6); v7 = fmaf(g3,bfhi(u3.w),v7);
    union { short8 s; uint u[4]; } r;
    r.u[0] = pk2bf(v0,v1); r.u[1] = pk2bf(v2,v3);
    r.u[2] = pk2bf(v4,v5); r.u[3] = pk2bf(v6,v7);
    return r.s;
}

// coords for one tap/px from REGISTER om values (n compile-time)
__device__ __forceinline__ void coords_tap_reg(
    const float* om, int irow, int jcol, int n, int4& cc, float4& bg)
{
    int di = n / 3, dj = n - di * 3;
    float offx = om[n];
    float offy = om[9 + n];
    float mv   = om[18 + n];
    float pxf = (float)(irow + di) + offx;
    float pyf = (float)(jcol + dj) + offy;
    float fx = floorf(pxf), fy = floorf(pyf);
    float qltx = fminf(fmaxf(fx,       0.f), 129.f);
    float qlty = fminf(fmaxf(fy,       0.f), 129.f);
    float qrbx = fminf(fmaxf(fx + 1.f, 0.f), 129.f);
    float qrby = fminf(fmaxf(fy + 1.f, 0.f), 129.f);
    float pxc  = fminf(fmaxf(pxf,      0.f), 129.f);
    float pyc  = fminf(fmaxf(pyf,      0.f), 129.f);
    float glt = (1.f + (qltx - pxc)) * (1.f + (qlty - pyc));
    float grb = (1.f - (qrbx - pxc)) * (1.f - (qrby - pyc));
    float glb = (1.f + (qltx - pxc)) * (1.f - (qrby - pyc));
    float grt = (1.f - (qrbx - pxc)) * (1.f + (qlty - pyc));
    cc.x = (int)qltx; cc.y = (int)qlty; cc.z = (int)qrbx; cc.w = (int)qrby;
    bg.x = glt * mv; bg.y = grb * mv; bg.z = glb * mv; bg.w = grt * mv;
}

// ---------------------------------------------------------------------------
// prep_x: blocks [0,128): NCHW fp32 -> padded NHWC bf16
//         blocks [128,1160): zero borders of xt and y1t
// ---------------------------------------------------------------------------
__global__ __launch_bounds__(256, 2) void prep_x(
    const float* __restrict__ x, ushort* __restrict__ xtt, ushort* __restrict__ y1t)
{
    int t = threadIdx.x, l = t & 63, wv = t >> 6;
    if (blockIdx.x < 128) {
        int c2 = l & 31, ps = l >> 5;
        int pix0w = blockIdx.x * 512 + wv * 128;
        int bq = pix0w >> 14;
        const float* xp0 = x + ((size_t)(bq * 64 + c2 * 2)) * HWSZ;
        ushort* xw = xtt + (size_t)bq * SLAB;
        #pragma unroll 8
        for (int p = 0; p < 64; ++p) {
            int pxi = (pix0w + p * 2 + ps) & (HWSZ - 1);
            int i = pxi >> 7, j = pxi & 127;
            uint u = pk2bf(xp0[pxi], xp0[pxi + HWSZ]);
            *(uint*)(xw + ((i + 1) * PADW + (j + 1)) * 64 + c2 * 2) = u;
        }
    } else {
        int idx = (blockIdx.x - 128) * 256 + t;
        if (idx >= 264192) return;
        ushort* buf = (idx >= 132096) ? y1t : xtt;
        int e_all = idx % 132096;
        int bq = e_all / 33024, e = e_all % 33024;
        int i, j, c;
        if (e < 8320)       { i = 0;   j = e >> 6; c = e & 63; }
        else if (e < 16640) { int e2 = e - 8320; i = 129; j = e2 >> 6; c = e2 & 63; }
        else                { int e2 = e - 16640; c = e2 & 63;
                              i = (e2 >> 7) + 1; j = ((e2 >> 6) & 1) ? 129 : 0; }
        buf[(size_t)bq * SLAB + (i * PADW + j) * 64 + c] = 0;
    }
}

// ---------------------------------------------------------------------------
// prep_w (layer split by explicit subtraction — sizes are not powers of 2)
// ---------------------------------------------------------------------------
__global__ void prep_w(
    const float* __restrict__ wc1, const float* __restrict__ wp1, const float* __restrict__ wm1,
    const float* __restrict__ wc2, const float* __restrict__ wp2, const float* __restrict__ wm2,
    ushort* __restrict__ wdf1, ushort* __restrict__ wof1,
    ushort* __restrict__ wdf2, ushort* __restrict__ wof2)
{
    int idx0 = blockIdx.x * 256 + threadIdx.x;
    union { __hip_bfloat16 h; ushort u; } cv;
    if (idx0 < 73728) {
        int lay = idx0 >= 36864;
        int idx = idx0 - lay * 36864;
        const float* wc = lay ? wc2 : wc1;
        ushort* dst = lay ? wdf2 : wdf1;
        int j = idx & 7, l = (idx >> 3) & 63;
        int nt = (idx >> 9) & 3, kc = (idx >> 11) & 1, tap = idx >> 12;
        int c  = kc * 32 + (l >> 4) * 8 + j;
        int oc = nt * 16 + (l & 15);
        cv.h = __float2bfloat16(wc[(oc * 64 + c) * 9 + tap]);
        dst[idx] = cv.u;
    } else if (idx0 < 110592) {
        int r = idx0 - 73728;
        int lay = r >= 18432;
        int idx = r - lay * 18432;
        const float* wp = lay ? wp2 : wp1;
        const float* wm = lay ? wm2 : wm1;
        ushort* dst = lay ? wof2 : wof1;
        int j = idx & 7, l = (idx >> 3) & 63;
        int nt = (idx >> 9) & 1, kc = (idx >> 10) & 1, tap = idx >> 11;
        int c  = kc * 32 + (l >> 4) * 8 + j;
        int ch = nt * 16 + (l & 15);
        float v = 0.f;
        if (ch < 18)      v = wp[(ch * 64 + c) * 9 + tap];
        else if (ch < 27) v = wm[((ch - 18) * 64 + c) * 9 + tap];
        cv.h = __float2bfloat16(v);
        dst[idx] = cv.u;
    }
}

// ---------------------------------------------------------------------------
// Fused layer. 256 thr / 4 waves; 4x16-px patch, wave wv owns row i0+wv.
//  stage: 11x23-cell window (32.4KB) chunk-swizzled -> LDS
//  phase 1: offset/mask conv via MFMA (A from window) -> omS LDS (wave-private)
//  om->regs: each lane loads its pixel's 27 offset/mask values once
//  phase 2: per tap: pure-VALU coords; 8 swizzled ds_read_b128 corner gathers
//           (global fallback if outside window); combine; 8 MFMA (N=64)
// ---------------------------------------------------------------------------
__global__ __launch_bounds__(256, 3) void fused(
    const ushort* __restrict__ xt, const ushort* __restrict__ wof,
    const float* __restrict__ bp, const float* __restrict__ bm,
    const ushort* __restrict__ wdf, const float* __restrict__ xres,
    float* __restrict__ outn, ushort* __restrict__ y1t, int mode)
{
    __shared__ __align__(16) char sm[SM_BYTES];
    const int t = threadIdx.x, l = t & 63, wv = t >> 6;
    // XCD swizzle: 1024 blocks, 128 contiguous per XCD
    const int lb = (blockIdx.x & 7) * 128 + (blockIdx.x >> 3);
    const int bb = lb >> 8;                  // batch (256 blocks each)
    const int patch = lb & 255;              // 32 row-groups x 8 col-groups
    const int i0 = (patch >> 3) * 4;
    const int j0 = (patch & 7) * 16;
    const int pc = l & 15, ck = l >> 4;      // lane's pixel-col / channel-chunk
    const ushort* xb = xt + (size_t)bb * SLAB;
    const char* xbb = (const char*)xb;

    // ---------- stage window ----------
    for (int s = t; s < NCELL * 8; s += 256) {
        int q = s & 7, cq = s >> 3;
        int c = cq % WC, r = cq / WC;
        int ip = min(max(i0 - 2 + r, 0), 129);
        int jp = min(max(j0 - 2 + c, 0), 129);
        uint4 v = *(const uint4*)(xbb + ((ip * PADW + jp) << 7) + (q << 4));
        *(uint4*)(sm + ((r * WC + c) << 7) + (((q ^ ((r + c) & 7))) << 4)) = v;
    }
    __syncthreads();

    // ---------- phase 1: offset/mask conv ----------
    f32x4 z4 = {0.f, 0.f, 0.f, 0.f};
    f32x4 oa0 = z4, oa1 = z4;
    #pragma unroll
    for (int tap = 0; tap < 9; ++tap) {
        int ti = tap / 3, tj = tap - ti * 3;
        short8 b00 = *(const short8*)(wof + (tap * 4 + 0) * 512 + l * 8);
        short8 b01 = *(const short8*)(wof + (tap * 4 + 1) * 512 + l * 8);
        short8 b10 = *(const short8*)(wof + (tap * 4 + 2) * 512 + l * 8);
        short8 b11 = *(const short8*)(wof + (tap * 4 + 3) * 512 + l * 8);
        int rA = wv + ti + 2;
        int cA = pc + tj + 2;
        int hA = (rA + cA) & 7;
        const char* cbp = sm + ((rA * WC + cA) << 7);
        short8 a0 = *(const short8*)(cbp + ((ck ^ hA) << 4));
        short8 a1 = *(const short8*)(cbp + (((ck + 4) ^ hA) << 4));
        oa0 = __builtin_amdgcn_mfma_f32_16x16x32_bf16(a0, b00, oa0, 0, 0, 0);
        oa1 = __builtin_amdgcn_mfma_f32_16x16x32_bf16(a0, b01, oa1, 0, 0, 0);
        oa0 = __builtin_amdgcn_mfma_f32_16x16x32_bf16(a1, b10, oa0, 0, 0, 0);
        oa1 = __builtin_amdgcn_mfma_f32_16x16x32_bf16(a1, b11, oa1, 0, 0, 0);
    }
    float* omS = (float*)(sm + OMS_OFF) + wv * 459;   // [27][17] per wave
    #pragma unroll
    for (int nt = 0; nt < 2; ++nt) {
        f32x4 oa = nt ? oa1 : oa0;
        int ch = nt * 16 + pc;                 // D: col = lane&15 = channel
        #pragma unroll
        for (int r = 0; r < 4; ++r) {
            if (ch < 27) {
                float v = oa[r] + ((ch < 18) ? bp[ch] : bm[ch - 18]);
                if (ch >= 18) v = 1.f / (1.f + __expf(-v));
                omS[ch * 17 + ck * 4 + r] = v;  // D: row = pixel-col
            }
        }
    }
    // om -> registers (wave-private LDS, no barrier needed)
    float om[27];
    #pragma unroll
    for (int ch = 0; ch < 27; ++ch) om[ch] = omS[ch * 17 + pc];

    // ---------- phase 2: deformable sampling + contraction ----------
    f32x4 acc0 = z4, acc1 = z4, acc2 = z4, acc3 = z4;
    const char* pb = xbb + ck * 16;
    const int irow = i0 + wv, jcol = j0 + pc;
    #pragma unroll
    for (int n = 0; n < 9; ++n) {
        const ushort* wbase = wdf + (size_t)n * 4096 + l * 8;
        short8 w00 = *(const short8*)(wbase);
        short8 w01 = *(const short8*)(wbase + 512);
        short8 w02 = *(const short8*)(wbase + 1024);
        short8 w03 = *(const short8*)(wbase + 1536);
        short8 w10 = *(const short8*)(wbase + 2048);
        short8 w11 = *(const short8*)(wbase + 2560);
        short8 w12 = *(const short8*)(wbase + 3072);
        short8 w13 = *(const short8*)(wbase + 3584);

        int4 cc; float4 g;
        coords_tap_reg(om, irow, jcol, n, cc, g);
        int rlt = cc.x - (i0 - 2), clt = cc.y - (j0 - 2);
        int rrb = cc.z - (i0 - 2), crb = cc.w - (j0 - 2);
        bool ok = ((uint)rlt < (uint)WR) & ((uint)rrb < (uint)WR) &
                  ((uint)clt < (uint)WC) & ((uint)crb < (uint)WC);
        short8 dltl, dlth, drbl, drbh, dlbl, dlbh, drtl, drth;
        if (ok) {
            int hlt = (rlt + clt) & 7, hrb = (rrb + crb) & 7;
            int hlb = (rlt + crb) & 7, hrt = (rrb + clt) & 7;
            const char* blt = sm + ((rlt * WC + clt) << 7);
            const char* brb = sm + ((rrb * WC + crb) << 7);
            const char* blb = sm + ((rlt * WC + crb) << 7);
            const char* brt = sm + ((rrb * WC + clt) << 7);
            dltl = *(const short8*)(blt + ((ck ^ hlt) << 4));
            dlth = *(const short8*)(blt + (((ck + 4) ^ hlt) << 4));
            drbl = *(const short8*)(brb + ((ck ^ hrb) << 4));
            drbh = *(const short8*)(brb + (((ck + 4) ^ hrb) << 4));
            dlbl = *(const short8*)(blb + ((ck ^ hlb) << 4));
            dlbh = *(const short8*)(blb + (((ck + 4) ^ hlb) << 4));
            drtl = *(const short8*)(brt + ((ck ^ hrt) << 4));
            drth = *(const short8*)(brt + (((ck + 4) ^ hrt) << 4));
        } else {
            int o_lt = (cc.x * PADW + cc.y) << 7;
            int o_rb = (cc.z * PADW + cc.w) << 7;
            int o_lb = (cc.x * PADW + cc.w) << 7;
            int o_rt = (cc.z * PADW + cc.y) << 7;
            dltl = *(const short8*)(pb + o_lt); dlth = *(const short8*)(pb + o_lt + 64);
            drbl = *(const short8*)(pb + o_rb); drbh = *(const short8*)(pb + o_rb + 64);
            dlbl = *(const short8*)(pb + o_lb); dlbh = *(const short8*)(pb + o_lb + 64);
            drtl = *(const short8*)(pb + o_rt); drth = *(const short8*)(pb + o_rt + 64);
        }
        short8 a0 = combine4(dltl, drbl, dlbl, drtl, g.x, g.y, g.z, g.w);
        short8 a1 = combine4(dlth, drbh, dlbh, drth, g.x, g.y, g.z, g.w);
        acc0 = __builtin_amdgcn_mfma_f32_16x16x32_bf16(a0, w00, acc0, 0, 0, 0);
        acc1 = __builtin_amdgcn_mfma_f32_16x16x32_bf16(a0, w01, acc1, 0, 0, 0);
        acc2 = __builtin_amdgcn_mfma_f32_16x16x32_bf16(a0, w02, acc2, 0, 0, 0);
        acc3 = __builtin_amdgcn_mfma_f32_16x16x32_bf16(a0, w03, acc3, 0, 0, 0);
        acc0 = __builtin_amdgcn_mfma_f32_16x16x32_bf16(a1, w10, acc0, 0, 0, 0);
        acc1 = __builtin_amdgcn_mfma_f32_16x16x32_bf16(a1, w11, acc1, 0, 0, 0);
        acc2 = __builtin_amdgcn_mfma_f32_16x16x32_bf16(a1, w12, acc2, 0, 0, 0);
        acc3 = __builtin_amdgcn_mfma_f32_16x16x32_bf16(a1, w13, acc3, 0, 0, 0);
    }

    // ---------- epilogue ----------
    if (mode == 0) {
        f32x4 av[4] = {acc0, acc1, acc2, acc3};
        #pragma unroll
        for (int nt = 0; nt < 4; ++nt) {
            int oc = nt * 16 + pc;               // D: col = oc
            size_t o = ((size_t)(bb * 64 + oc)) * HWSZ + (i0 + wv) * 128 + j0 + ck * 4;
            float4 rsd = *(const float4*)(xres + o);
            float4 vv;
            vv.x = av[nt][0] + rsd.x; vv.y = av[nt][1] + rsd.y;
            vv.z = av[nt][2] + rsd.z; vv.w = av[nt][3] + rsd.w;
            *(float4*)(outn + o) = vv;
        }
    } else {
        __syncthreads();
        float* T = (float*)sm;                   // [64 oc][65] overlays window
        f32x4 av[4] = {acc0, acc1, acc2, acc3};
        #pragma unroll
        for (int nt = 0; nt < 4; ++nt) {
            int oc = nt * 16 + pc;
            #pragma unroll
            for (int r = 0; r < 4; ++r) {
                int plin = wv * 16 + ck * 4 + r;  // (row wv, col ck*4+r)
                T[oc * 65 + plin] = fmaxf(av[nt][r], 0.f);
            }
        }
        __syncthreads();
        int plin = t >> 2, oc0 = (t & 3) * 16;
        int prow = plin >> 4, pcol = plin & 15;
        ushort* dst = y1t + (size_t)bb * SLAB +
                      ((i0 + prow + 1) * PADW + (j0 + pcol + 1)) * 64 + oc0;
        uint w[8];
        #pragma unroll
        for (int k2 = 0; k2 < 8; ++k2)
            w[k2] = pk2bf(T[(oc0 + k2 * 2) * 65 + plin],
                          T[(oc0 + k2 * 2 + 1) * 65 + plin]);
        *(uint4*)dst       = make_uint4(w[0], w[1], w[2], w[3]);
        *(uint4*)(dst + 8) = make_uint4(w[4], w[5], w[6], w[7]);
    }
}

// ---------------------------------------------------------------------------
extern "C" void kernel_launch(void* const* d_in, const int* in_sizes, int n_in,
                              void* d_out, int out_size, void* d_ws, size_t ws_size,
                              hipStream_t stream)
{
    const float* x      = (const float*)d_in[0];
    const float* d1_w_p = (const float*)d_in[1];
    const float* d1_b_p = (const float*)d_in[2];
    const float* d1_w_m = (const float*)d_in[3];
    const float* d1_b_m = (const float*)d_in[4];
    const float* d1_w_c = (const float*)d_in[5];
    const float* d2_w_p = (const float*)d_in[6];
    const float* d2_b_p = (const float*)d_in[7];
    const float* d2_w_m = (const float*)d_in[8];
    const float* d2_b_m = (const float*)d_in[9];
    const float* d2_w_c = (const float*)d_in[10];
    float* out = (float*)d_out;

    char* ws = (char*)d_ws;
    ushort* xtt  = (ushort*)(ws);               //  8,652,800 B padded NHWC bf16 x
    ushort* y1t  = (ushort*)(ws + 8652800);     //  8,652,800 B padded NHWC bf16 y1
    ushort* wdf1 = (ushort*)(ws + 17305600);
    ushort* wof1 = (ushort*)(ws + 17379328);
    ushort* wdf2 = (ushort*)(ws + 17416192);
    ushort* wof2 = (ushort*)(ws + 17489920);

    prep_w<<<432, 256, 0, stream>>>(d1_w_c, d1_w_p, d1_w_m, d2_w_c, d2_w_p, d2_w_m,
                                    wdf1, wof1, wdf2, wof2);
    prep_x<<<1160, 256, 0, stream>>>(x, xtt, y1t);

    fused<<<1024, 256, 0, stream>>>(xtt, wof1, d1_b_p, d1_b_m, wdf1,
                                    nullptr, nullptr, y1t, 1);
    fused<<<1024, 256, 0, stream>>>(y1t, wof2, d2_b_p, d2_b_m, wdf2,
                                    x, out, nullptr, 0);
}

// Round 9
// 82.484 us; speedup vs baseline: 1.0131x; 1.0131x over previous
//
#include <hip/hip_runtime.h>
#include <hip/hip_bf16.h>
#include <math.h>

typedef __attribute__((ext_vector_type(8))) short short8;
typedef __attribute__((ext_vector_type(4))) float f32x4;
typedef unsigned int uint;
typedef unsigned short ushort;

#define HWSZ 16384
#define PADW 130
#define SLAB (PADW*PADW*64)
// window: 11 rows x 23 cols of 128B cells, origin (i0-2, j0-2) padded coords
#define WR 11
#define WC 23
#define NCELL (WR*WC)            // 253
#define OMS_OFF 32384            // bytes: 253*128
#define SM_BYTES (32384 + 4*27*17*4)

__device__ __forceinline__ uint pk2bf(float a, float b) {
    union { __hip_bfloat162 h; uint u; } cv;
    cv.h = __float22bfloat162_rn(make_float2(a, b)); return cv.u;
}
__device__ __forceinline__ float bflo(uint u){ return __uint_as_float(u << 16); }
__device__ __forceinline__ float bfhi(uint u){ return __uint_as_float(u & 0xffff0000u); }

__device__ __forceinline__ short8 combine4(short8 s0, short8 s1, short8 s2, short8 s3,
                                           float g0, float g1, float g2, float g3)
{
    uint4 u0 = *(uint4*)&s0, u1 = *(uint4*)&s1, u2 = *(uint4*)&s2, u3 = *(uint4*)&s3;
    float v0,v1,v2,v3,v4,v5,v6,v7;
    v0 = g0*bflo(u0.x); v1 = g0*bfhi(u0.x); v2 = g0*bflo(u0.y); v3 = g0*bfhi(u0.y);
    v4 = g0*bflo(u0.z); v5 = g0*bfhi(u0.z); v6 = g0*bflo(u0.w); v7 = g0*bfhi(u0.w);
    v0 = fmaf(g1,bflo(u1.x),v0); v1 = fmaf(g1,bfhi(u1.x),v1);
    v2 = fmaf(g1,bflo(u1.y),v2); v3 = fmaf(g1,bfhi(u1.y),v3);
    v4 = fmaf(g1,bflo(u1.z),v4); v5 = fmaf(g1,bfhi(u1.z),v5);
    v6 = fmaf(g1,bflo(u1.w),v6); v7 = fmaf(g1,bfhi(u1.w),v7);
    v0 = fmaf(g2,bflo(u2.x),v0); v1 = fmaf(g2,bfhi(u2.x),v1);
    v2 = fmaf(g2,bflo(u2.y),v2); v3 = fmaf(g2,bfhi(u2.y),v3);
    v4 = fmaf(g2,bflo(u2.z),v4); v5 = fmaf(g2,bfhi(u2.z),v5);
    v6 = fmaf(g2,bflo(u2.w),v6); v7 = fmaf(g2,bfhi(u2.w),v7);
    v0 = fmaf(g3,bflo(u3.x),v0); v1 = fmaf(g3,bfhi(u3.x),v1);
    v2 = fmaf(g3,bflo(u3.y),v2); v3 = fmaf(g3,bfhi(u3.y),v3);
    v4 = fmaf(g3,bflo(u3.z),v4); v5 = fmaf(g3,bfhi(u3.z),v5);
    v6 = fmaf(g3,bflo(u3.w),v6); v7 = fmaf(g3,bfhi(u3.w),v7);
    union { short8 s; uint u[4]; } r;
    r.u[0] = pk2bf(v0,v1); r.u[1] = pk2bf(v2,v3);
    r.u[2] = pk2bf(v4,v5); r.u[3] = pk2bf(v6,v7);
    return r.s;
}

// coords for one tap/px from wave-private omS LDS (dirty-path / coords pass)
__device__ __forceinline__ void coords_tap_lds(
    const float* __restrict__ omS, int pc, int irow, int jcol, int n,
    int4& cc, float4& bg)
{
    int di = n / 3, dj = n - di * 3;
    float offx = omS[n * 17 + pc];
    float offy = omS[(9 + n) * 17 + pc];
    float mv   = omS[(18 + n) * 17 + pc];
    float pxf = (float)(irow + di) + offx;
    float pyf = (float)(jcol + dj) + offy;
    float fx = floorf(pxf), fy = floorf(pyf);
    float qltx = fminf(fmaxf(fx,       0.f), 129.f);
    float qlty = fminf(fmaxf(fy,       0.f), 129.f);
    float qrbx = fminf(fmaxf(fx + 1.f, 0.f), 129.f);
    float qrby = fminf(fmaxf(fy + 1.f, 0.f), 129.f);
    float pxc  = fminf(fmaxf(pxf,      0.f), 129.f);
    float pyc  = fminf(fmaxf(pyf,      0.f), 129.f);
    float glt = (1.f + (qltx - pxc)) * (1.f + (qlty - pyc));
    float grb = (1.f - (qrbx - pxc)) * (1.f - (qrby - pyc));
    float glb = (1.f + (qltx - pxc)) * (1.f - (qrby - pyc));
    float grt = (1.f - (qrbx - pxc)) * (1.f + (qlty - pyc));
    cc.x = (int)qltx; cc.y = (int)qlty; cc.z = (int)qrbx; cc.w = (int)qrby;
    bg.x = glt * mv; bg.y = grb * mv; bg.z = glb * mv; bg.w = grt * mv;
}

// ---------------------------------------------------------------------------
// prep: blocks [0,432): fragment-major weight buffers (both layers)
//       blocks [432,560): NCHW fp32 -> padded NHWC bf16
//       blocks [560,1592): zero borders of xt and y1t
// ---------------------------------------------------------------------------
__global__ __launch_bounds__(256, 2) void prep(
    const float* __restrict__ x, ushort* __restrict__ xtt, ushort* __restrict__ y1t,
    const float* __restrict__ wc1, const float* __restrict__ wp1, const float* __restrict__ wm1,
    const float* __restrict__ wc2, const float* __restrict__ wp2, const float* __restrict__ wm2,
    ushort* __restrict__ wdf1, ushort* __restrict__ wof1,
    ushort* __restrict__ wdf2, ushort* __restrict__ wof2)
{
    int t = threadIdx.x;
    if (blockIdx.x < 432) {
        int idx0 = blockIdx.x * 256 + t;
        union { __hip_bfloat16 h; ushort u; } cv;
        if (idx0 < 73728) {
            int lay = idx0 >= 36864;
            int idx = idx0 - lay * 36864;
            const float* wc = lay ? wc2 : wc1;
            ushort* dst = lay ? wdf2 : wdf1;
            int j = idx & 7, l = (idx >> 3) & 63;
            int nt = (idx >> 9) & 3, kc = (idx >> 11) & 1, tap = idx >> 12;
            int c  = kc * 32 + (l >> 4) * 8 + j;
            int oc = nt * 16 + (l & 15);
            cv.h = __float2bfloat16(wc[(oc * 64 + c) * 9 + tap]);
            dst[idx] = cv.u;
        } else if (idx0 < 110592) {
            int r = idx0 - 73728;
            int lay = r >= 18432;
            int idx = r - lay * 18432;
            const float* wp = lay ? wp2 : wp1;
            const float* wm = lay ? wm2 : wm1;
            ushort* dst = lay ? wof2 : wof1;
            int j = idx & 7, l = (idx >> 3) & 63;
            int nt = (idx >> 9) & 1, kc = (idx >> 10) & 1, tap = idx >> 11;
            int c  = kc * 32 + (l >> 4) * 8 + j;
            int ch = nt * 16 + (l & 15);
            float v = 0.f;
            if (ch < 18)      v = wp[(ch * 64 + c) * 9 + tap];
            else if (ch < 27) v = wm[((ch - 18) * 64 + c) * 9 + tap];
            cv.h = __float2bfloat16(v);
            dst[idx] = cv.u;
        }
        return;
    }
    int bx = blockIdx.x - 432;
    int l = t & 63, wv = t >> 6;
    if (bx < 128) {
        int c2 = l & 31, ps = l >> 5;
        int pix0w = bx * 512 + wv * 128;
        int bq = pix0w >> 14;
        const float* xp0 = x + ((size_t)(bq * 64 + c2 * 2)) * HWSZ;
        ushort* xw = xtt + (size_t)bq * SLAB;
        #pragma unroll 8
        for (int p = 0; p < 64; ++p) {
            int pxi = (pix0w + p * 2 + ps) & (HWSZ - 1);
            int i = pxi >> 7, j = pxi & 127;
            uint u = pk2bf(xp0[pxi], xp0[pxi + HWSZ]);
            *(uint*)(xw + ((i + 1) * PADW + (j + 1)) * 64 + c2 * 2) = u;
        }
    } else {
        int idx = (bx - 128) * 256 + t;
        if (idx >= 264192) return;
        ushort* buf = (idx >= 132096) ? y1t : xtt;
        int e_all = idx % 132096;
        int bq = e_all / 33024, e = e_all % 33024;
        int i, j, c;
        if (e < 8320)       { i = 0;   j = e >> 6; c = e & 63; }
        else if (e < 16640) { int e2 = e - 8320; i = 129; j = e2 >> 6; c = e2 & 63; }
        else                { int e2 = e - 16640; c = e2 & 63;
                              i = (e2 >> 7) + 1; j = ((e2 >> 6) & 1) ? 129 : 0; }
        buf[(size_t)bq * SLAB + (i * PADW + j) * 64 + c] = 0;
    }
}

// ---------------------------------------------------------------------------
// Fused layer. 256 thr / 4 waves; 4x16-px patch, wave wv owns row i0+wv.
//  stage 11x23-cell window -> LDS (chunk-swizzled)
//  phase 1: offset/mask conv via MFMA (2-deep weight pipeline) -> omS LDS
//  phase 2: coords pass (all 9 taps) -> ONE wave-uniform branch:
//    clean (>99%): fully-unrolled branch-free loop, 2-deep corner double-
//                  buffer (cb0/cb1), weight loads hoisted above combine
//    dirty (rare): exact per-tap fallback (LDS or global per lane)
// ---------------------------------------------------------------------------
#define MFB(a,b,c) __builtin_amdgcn_mfma_f32_16x16x32_bf16(a,b,c,0,0,0)

#define LOADC(CB, nn) { \
    uint cp_ = cpack[nn]; \
    int rlt_ = cp_ & 255, clt_ = (cp_ >> 8) & 255, rrb_ = (cp_ >> 16) & 255, crb_ = cp_ >> 24; \
    const char* blt_ = sm + ((rlt_ * WC + clt_) << 7); \
    const char* brb_ = sm + ((rrb_ * WC + crb_) << 7); \
    const char* blb_ = sm + ((rlt_ * WC + crb_) << 7); \
    const char* brt_ = sm + ((rrb_ * WC + clt_) << 7); \
    int hlt_ = (rlt_ + clt_) & 7, hrb_ = (rrb_ + crb_) & 7; \
    int hlb_ = (rlt_ + crb_) & 7, hrt_ = (rrb_ + clt_) & 7; \
    CB[0] = *(const short8*)(blt_ + ((ck ^ hlt_) << 4)); \
    CB[1] = *(const short8*)(blt_ + (((ck + 4) ^ hlt_) << 4)); \
    CB[2] = *(const short8*)(brb_ + ((ck ^ hrb_) << 4)); \
    CB[3] = *(const short8*)(brb_ + (((ck + 4) ^ hrb_) << 4)); \
    CB[4] = *(const short8*)(blb_ + ((ck ^ hlb_) << 4)); \
    CB[5] = *(const short8*)(blb_ + (((ck + 4) ^ hlb_) << 4)); \
    CB[6] = *(const short8*)(brt_ + ((ck ^ hrt_) << 4)); \
    CB[7] = *(const short8*)(brt_ + (((ck + 4) ^ hrt_) << 4)); }

#define TAP(nn, CBC, CBN) { \
    const ushort* wb_ = wdf + (size_t)(nn) * 4096 + l * 8; \
    short8 w00 = *(const short8*)(wb_); \
    short8 w01 = *(const short8*)(wb_ + 512); \
    short8 w02 = *(const short8*)(wb_ + 1024); \
    short8 w03 = *(const short8*)(wb_ + 1536); \
    short8 w10 = *(const short8*)(wb_ + 2048); \
    short8 w11 = *(const short8*)(wb_ + 2560); \
    short8 w12 = *(const short8*)(wb_ + 3072); \
    short8 w13 = *(const short8*)(wb_ + 3584); \
    if ((nn) < 8) LOADC(CBN, (nn) + 1); \
    float4 g_ = gw[nn]; \
    short8 a0_ = combine4(CBC[0], CBC[2], CBC[4], CBC[6], g_.x, g_.y, g_.z, g_.w); \
    short8 a1_ = combine4(CBC[1], CBC[3], CBC[5], CBC[7], g_.x, g_.y, g_.z, g_.w); \
    acc0 = MFB(a0_, w00, acc0); acc1 = MFB(a0_, w01, acc1); \
    acc2 = MFB(a0_, w02, acc2); acc3 = MFB(a0_, w03, acc3); \
    acc0 = MFB(a1_, w10, acc0); acc1 = MFB(a1_, w11, acc1); \
    acc2 = MFB(a1_, w12, acc2); acc3 = MFB(a1_, w13, acc3); }

__global__ __launch_bounds__(256, 2) void fused(
    const ushort* __restrict__ xt, const ushort* __restrict__ wof,
    const float* __restrict__ bp, const float* __restrict__ bm,
    const ushort* __restrict__ wdf, const float* __restrict__ xres,
    float* __restrict__ outn, ushort* __restrict__ y1t, int mode)
{
    __shared__ __align__(16) char sm[SM_BYTES];
    const int t = threadIdx.x, l = t & 63, wv = t >> 6;
    const int lb = (blockIdx.x & 7) * 128 + (blockIdx.x >> 3);
    const int bb = lb >> 8;
    const int patch = lb & 255;
    const int i0 = (patch >> 3) * 4;
    const int j0 = (patch & 7) * 16;
    const int pc = l & 15, ck = l >> 4;
    const ushort* xb = xt + (size_t)bb * SLAB;
    const char* xbb = (const char*)xb;

    // ---------- stage window ----------
    for (int s = t; s < NCELL * 8; s += 256) {
        int q = s & 7, cq = s >> 3;
        int c = cq % WC, r = cq / WC;
        int ip = min(max(i0 - 2 + r, 0), 129);
        int jp = min(max(j0 - 2 + c, 0), 129);
        uint4 v = *(const uint4*)(xbb + ((ip * PADW + jp) << 7) + (q << 4));
        *(uint4*)(sm + ((r * WC + c) << 7) + (((q ^ ((r + c) & 7))) << 4)) = v;
    }
    __syncthreads();

    // ---------- phase 1: offset/mask conv (2-deep weight pipeline) ----------
    f32x4 z4 = {0.f, 0.f, 0.f, 0.f};
    f32x4 oa0 = z4, oa1 = z4;
    short8 pwA[4], pwB[4];
    {
        const ushort* w0_ = wof + l * 8;
        pwA[0] = *(const short8*)(w0_);
        pwA[1] = *(const short8*)(w0_ + 512);
        pwA[2] = *(const short8*)(w0_ + 1024);
        pwA[3] = *(const short8*)(w0_ + 1536);
    }
#define PTAP(tt, WA, WB) { \
    if ((tt) < 8) { \
        const ushort* wn_ = wof + ((tt) + 1) * 2048 + l * 8; \
        WB[0] = *(const short8*)(wn_); \
        WB[1] = *(const short8*)(wn_ + 512); \
        WB[2] = *(const short8*)(wn_ + 1024); \
        WB[3] = *(const short8*)(wn_ + 1536); } \
    int ti_ = (tt) / 3, tj_ = (tt) - ti_ * 3; \
    int rA_ = wv + ti_ + 2, cA_ = pc + tj_ + 2; \
    int hA_ = (rA_ + cA_) & 7; \
    const char* cbp_ = sm + ((rA_ * WC + cA_) << 7); \
    short8 a0_ = *(const short8*)(cbp_ + ((ck ^ hA_) << 4)); \
    short8 a1_ = *(const short8*)(cbp_ + (((ck + 4) ^ hA_) << 4)); \
    oa0 = MFB(a0_, WA[0], oa0); oa1 = MFB(a0_, WA[1], oa1); \
    oa0 = MFB(a1_, WA[2], oa0); oa1 = MFB(a1_, WA[3], oa1); }
    PTAP(0, pwA, pwB); PTAP(1, pwB, pwA); PTAP(2, pwA, pwB);
    PTAP(3, pwB, pwA); PTAP(4, pwA, pwB); PTAP(5, pwB, pwA);
    PTAP(6, pwA, pwB); PTAP(7, pwB, pwA); PTAP(8, pwA, pwB);
#undef PTAP

    float* omS = (float*)(sm + OMS_OFF) + wv * 459;   // [27][17] per wave
    #pragma unroll
    for (int nt = 0; nt < 2; ++nt) {
        f32x4 oa = nt ? oa1 : oa0;
        int ch = nt * 16 + pc;
        #pragma unroll
        for (int r = 0; r < 4; ++r) {
            if (ch < 27) {
                float v = oa[r] + ((ch < 18) ? bp[ch] : bm[ch - 18]);
                if (ch >= 18) v = 1.f / (1.f + __expf(-v));
                omS[ch * 17 + ck * 4 + r] = v;
            }
        }
    }

    // ---------- phase 2: coords pass (all taps), then wave-uniform branch ----
    f32x4 acc0 = z4, acc1 = z4, acc2 = z4, acc3 = z4;
    const int irow = i0 + wv, jcol = j0 + pc;
    uint cpack[9]; float4 gw[9];
    bool okall = true;
    #pragma unroll
    for (int n = 0; n < 9; ++n) {
        int4 cc; float4 g;
        coords_tap_lds(omS, pc, irow, jcol, n, cc, g);
        int rlt = cc.x - (i0 - 2), clt = cc.y - (j0 - 2);
        int rrb = cc.z - (i0 - 2), crb = cc.w - (j0 - 2);
        okall = okall & ((uint)rlt < (uint)WR) & ((uint)rrb < (uint)WR) &
                        ((uint)clt < (uint)WC) & ((uint)crb < (uint)WC);
        cpack[n] = (uint)(rlt & 255) | ((uint)(clt & 255) << 8) |
                   ((uint)(rrb & 255) << 16) | ((uint)(crb & 255) << 24);
        gw[n] = g;
    }

    if (__all(okall)) {
        // ---- clean path: branch-free, 2-deep corner double-buffer ----
        short8 cb0[8], cb1[8];
        LOADC(cb0, 0);
        TAP(0, cb0, cb1); TAP(1, cb1, cb0); TAP(2, cb0, cb1);
        TAP(3, cb1, cb0); TAP(4, cb0, cb1); TAP(5, cb1, cb0);
        TAP(6, cb0, cb1); TAP(7, cb1, cb0); TAP(8, cb0, cb1);
    } else {
        // ---- dirty path: exact per-tap fallback (rare) ----
        const char* pb = xbb + ck * 16;
        #pragma unroll
        for (int n = 0; n < 9; ++n) {
            const ushort* wbase = wdf + (size_t)n * 4096 + l * 8;
            short8 w00 = *(const short8*)(wbase);
            short8 w01 = *(const short8*)(wbase + 512);
            short8 w02 = *(const short8*)(wbase + 1024);
            short8 w03 = *(const short8*)(wbase + 1536);
            short8 w10 = *(const short8*)(wbase + 2048);
            short8 w11 = *(const short8*)(wbase + 2560);
            short8 w12 = *(const short8*)(wbase + 3072);
            short8 w13 = *(const short8*)(wbase + 3584);
            int4 cc; float4 g;
            coords_tap_lds(omS, pc, irow, jcol, n, cc, g);
            int rlt = cc.x - (i0 - 2), clt = cc.y - (j0 - 2);
            int rrb = cc.z - (i0 - 2), crb = cc.w - (j0 - 2);
            bool ok = ((uint)rlt < (uint)WR) & ((uint)rrb < (uint)WR) &
                      ((uint)clt < (uint)WC) & ((uint)crb < (uint)WC);
            short8 dltl, dlth, drbl, drbh, dlbl, dlbh, drtl, drth;
            if (ok) {
                int hlt = (rlt + clt) & 7, hrb = (rrb + crb) & 7;
                int hlb = (rlt + crb) & 7, hrt = (rrb + clt) & 7;
                const char* blt = sm + ((rlt * WC + clt) << 7);
                const char* brb = sm + ((rrb * WC + crb) << 7);
                const char* blb = sm + ((rlt * WC + crb) << 7);
                const char* brt = sm + ((rrb * WC + clt) << 7);
                dltl = *(const short8*)(blt + ((ck ^ hlt) << 4));
                dlth = *(const short8*)(blt + (((ck + 4) ^ hlt) << 4));
                drbl = *(const short8*)(brb + ((ck ^ hrb) << 4));
                drbh = *(const short8*)(brb + (((ck + 4) ^ hrb) << 4));
                dlbl = *(const short8*)(blb + ((ck ^ hlb) << 4));
                dlbh = *(const short8*)(blb + (((ck + 4) ^ hlb) << 4));
                drtl = *(const short8*)(brt + ((ck ^ hrt) << 4));
                drth = *(const short8*)(brt + (((ck + 4) ^ hrt) << 4));
            } else {
                int o_lt = (cc.x * PADW + cc.y) << 7;
                int o_rb = (cc.z * PADW + cc.w) << 7;
                int o_lb = (cc.x * PADW + cc.w) << 7;
                int o_rt = (cc.z * PADW + cc.y) << 7;
                dltl = *(const short8*)(pb + o_lt); dlth = *(const short8*)(pb + o_lt + 64);
                drbl = *(const short8*)(pb + o_rb); drbh = *(const short8*)(pb + o_rb + 64);
                dlbl = *(const short8*)(pb + o_lb); dlbh = *(const short8*)(pb + o_lb + 64);
                drtl = *(const short8*)(pb + o_rt); drth = *(const short8*)(pb + o_rt + 64);
            }
            short8 a0 = combine4(dltl, drbl, dlbl, drtl, g.x, g.y, g.z, g.w);
            short8 a1 = combine4(dlth, drbh, dlbh, drth, g.x, g.y, g.z, g.w);
            acc0 = MFB(a0, w00, acc0); acc1 = MFB(a0, w01, acc1);
            acc2 = MFB(a0, w02, acc2); acc3 = MFB(a0, w03, acc3);
            acc0 = MFB(a1, w10, acc0); acc1 = MFB(a1, w11, acc1);
            acc2 = MFB(a1, w12, acc2); acc3 = MFB(a1, w13, acc3);
        }
    }

    // ---------- epilogue ----------
    if (mode == 0) {
        f32x4 av[4] = {acc0, acc1, acc2, acc3};
        #pragma unroll
        for (int nt = 0; nt < 4; ++nt) {
            int oc = nt * 16 + pc;
            size_t o = ((size_t)(bb * 64 + oc)) * HWSZ + (i0 + wv) * 128 + j0 + ck * 4;
            float4 rsd = *(const float4*)(xres + o);
            float4 vv;
            vv.x = av[nt][0] + rsd.x; vv.y = av[nt][1] + rsd.y;
            vv.z = av[nt][2] + rsd.z; vv.w = av[nt][3] + rsd.w;
            *(float4*)(outn + o) = vv;
        }
    } else {
        __syncthreads();
        float* T = (float*)sm;                   // [64 oc][65] overlays window
        f32x4 av[4] = {acc0, acc1, acc2, acc3};
        #pragma unroll
        for (int nt = 0; nt < 4; ++nt) {
            int oc = nt * 16 + pc;
            #pragma unroll
            for (int r = 0; r < 4; ++r) {
                int plin = wv * 16 + ck * 4 + r;
                T[oc * 65 + plin] = fmaxf(av[nt][r], 0.f);
            }
        }
        __syncthreads();
        int plin = t >> 2, oc0 = (t & 3) * 16;
        int prow = plin >> 4, pcol = plin & 15;
        ushort* dst = y1t + (size_t)bb * SLAB +
                      ((i0 + prow + 1) * PADW + (j0 + pcol + 1)) * 64 + oc0;
        uint w[8];
        #pragma unroll
        for (int k2 = 0; k2 < 8; ++k2)
            w[k2] = pk2bf(T[(oc0 + k2 * 2) * 65 + plin],
                          T[(oc0 + k2 * 2 + 1) * 65 + plin]);
        *(uint4*)dst       = make_uint4(w[0], w[1], w[2], w[3]);
        *(uint4*)(dst + 8) = make_uint4(w[4], w[5], w[6], w[7]);
    }
}

// ---------------------------------------------------------------------------
extern "C" void kernel_launch(void* const* d_in, const int* in_sizes, int n_in,
                              void* d_out, int out_size, void* d_ws, size_t ws_size,
                              hipStream_t stream)
{
    const float* x      = (const float*)d_in[0];
    const float* d1_w_p = (const float*)d_in[1];
    const float* d1_b_p = (const float*)d_in[2];
    const float* d1_w_m = (const float*)d_in[3];
    const float* d1_b_m = (const float*)d_in[4];
    const float* d1_w_c = (const float*)d_in[5];
    const float* d2_w_p = (const float*)d_in[6];
    const float* d2_b_p = (const float*)d_in[7];
    const float* d2_w_m = (const float*)d_in[8];
    const float* d2_b_m = (const float*)d_in[9];
    const float* d2_w_c = (const float*)d_in[10];
    float* out = (float*)d_out;

    char* ws = (char*)d_ws;
    ushort* xtt  = (ushort*)(ws);               //  8,652,800 B padded NHWC bf16 x
    ushort* y1t  = (ushort*)(ws + 8652800);     //  8,652,800 B padded NHWC bf16 y1
    ushort* wdf1 = (ushort*)(ws + 17305600);
    ushort* wof1 = (ushort*)(ws + 17379328);
    ushort* wdf2 = (ushort*)(ws + 17416192);
    ushort* wof2 = (ushort*)(ws + 17489920);

    prep<<<1592, 256, 0, stream>>>(x, xtt, y1t,
                                   d1_w_c, d1_w_p, d1_w_m, d2_w_c, d2_w_p, d2_w_m,
                                   wdf1, wof1, wdf2, wof2);

    fused<<<1024, 256, 0, stream>>>(xtt, wof1, d1_b_p, d1_b_m, wdf1,
                                    nullptr, nullptr, y1t, 1);
    fused<<<1024, 256, 0, stream>>>(y1t, wof2, d2_b_p, d2_b_m, wdf2,
                                    x, out, nullptr, 0);
}

// Round 10
// 73.664 us; speedup vs baseline: 1.1344x; 1.1197x over previous
//
#include <hip/hip_runtime.h>
#include <hip/hip_bf16.h>
#include <math.h>

typedef __attribute__((ext_vector_type(8))) short short8;
typedef __attribute__((ext_vector_type(16))) float f32x16;
typedef unsigned int uint;
typedef unsigned short ushort;

#define HWSZ 16384
#define PADW 130
#define SLAB (PADW*PADW*64)
// window: 15 rows x 23 cols of 128B cells at 144B stride (bank-rotating)
#define WR 15
#define WC 23
#define NCELL (WR*WC)            // 345
#define CSTRIDE 144
#define OMS_OFF (NCELL*CSTRIDE)  // 49680
#define SM_BYTES (OMS_OFF + 4*27*33*4)   // 63936 <= 64KB

__device__ __forceinline__ uint pk2bf(float a, float b) {
    union { __hip_bfloat162 h; uint u; } cv;
    cv.h = __float22bfloat162_rn(make_float2(a, b)); return cv.u;
}
__device__ __forceinline__ float bflo(uint u){ return __uint_as_float(u << 16); }
__device__ __forceinline__ float bfhi(uint u){ return __uint_as_float(u & 0xffff0000u); }

__device__ __forceinline__ short8 combine4(short8 s0, short8 s1, short8 s2, short8 s3,
                                           float g0, float g1, float g2, float g3)
{
    uint4 u0 = *(uint4*)&s0, u1 = *(uint4*)&s1, u2 = *(uint4*)&s2, u3 = *(uint4*)&s3;
    float v0,v1,v2,v3,v4,v5,v6,v7;
    v0 = g0*bflo(u0.x); v1 = g0*bfhi(u0.x); v2 = g0*bflo(u0.y); v3 = g0*bfhi(u0.y);
    v4 = g0*bflo(u0.z); v5 = g0*bfhi(u0.z); v6 = g0*bflo(u0.w); v7 = g0*bfhi(u0.w);
    v0 = fmaf(g1,bflo(u1.x),v0); v1 = fmaf(g1,bfhi(u1.x),v1);
    v2 = fmaf(g1,bflo(u1.y),v2); v3 = fmaf(g1,bfhi(u1.y),v3);
    v4 = fmaf(g1,bflo(u1.z),v4); v5 = fmaf(g1,bfhi(u1.z),v5);
    v6 = fmaf(g1,bflo(u1.w),v6); v7 = fmaf(g1,bfhi(u1.w),v7);
    v0 = fmaf(g2,bflo(u2.x),v0); v1 = fmaf(g2,bfhi(u2.x),v1);
    v2 = fmaf(g2,bflo(u2.y),v2); v3 = fmaf(g2,bfhi(u2.y),v3);
    v4 = fmaf(g2,bflo(u2.z),v4); v5 = fmaf(g2,bfhi(u2.z),v5);
    v6 = fmaf(g2,bflo(u2.w),v6); v7 = fmaf(g2,bfhi(u2.w),v7);
    v0 = fmaf(g3,bflo(u3.x),v0); v1 = fmaf(g3,bfhi(u3.x),v1);
    v2 = fmaf(g3,bflo(u3.y),v2); v3 = fmaf(g3,bfhi(u3.y),v3);
    v4 = fmaf(g3,bflo(u3.z),v4); v5 = fmaf(g3,bfhi(u3.z),v5);
    v6 = fmaf(g3,bflo(u3.w),v6); v7 = fmaf(g3,bfhi(u3.w),v7);
    union { short8 s; uint u[4]; } r;
    r.u[0] = pk2bf(v0,v1); r.u[1] = pk2bf(v2,v3);
    r.u[2] = pk2bf(v4,v5); r.u[3] = pk2bf(v6,v7);
    return r.s;
}

// coords for one tap/pixel from wave-private omS (stride-33 rows, px index p)
__device__ __forceinline__ void coords_tap_lds(
    const float* __restrict__ omS, int p, int irow, int jcol, int n,
    int4& cc, float4& bg)
{
    int di = n / 3, dj = n - di * 3;
    float offx = omS[n * 33 + p];
    float offy = omS[(9 + n) * 33 + p];
    float mv   = omS[(18 + n) * 33 + p];
    float pxf = (float)(irow + di) + offx;
    float pyf = (float)(jcol + dj) + offy;
    float fx = floorf(pxf), fy = floorf(pyf);
    float qltx = fminf(fmaxf(fx,       0.f), 129.f);
    float qlty = fminf(fmaxf(fy,       0.f), 129.f);
    float qrbx = fminf(fmaxf(fx + 1.f, 0.f), 129.f);
    float qrby = fminf(fmaxf(fy + 1.f, 0.f), 129.f);
    float pxc  = fminf(fmaxf(pxf,      0.f), 129.f);
    float pyc  = fminf(fmaxf(pyf,      0.f), 129.f);
    float glt = (1.f + (qltx - pxc)) * (1.f + (qlty - pyc));
    float grb = (1.f - (qrbx - pxc)) * (1.f - (qrby - pyc));
    float glb = (1.f + (qltx - pxc)) * (1.f - (qrby - pyc));
    float grt = (1.f - (qrbx - pxc)) * (1.f + (qlty - pyc));
    cc.x = (int)qltx; cc.y = (int)qlty; cc.z = (int)qrbx; cc.w = (int)qrby;
    bg.x = glt * mv; bg.y = grb * mv; bg.z = glb * mv; bg.w = grt * mv;
}

// ---------------------------------------------------------------------------
// prep: blocks [0,432): fragment-major weight buffers (32x32-MFMA layouts)
//       blocks [432,560): NCHW fp32 -> padded NHWC bf16
//       blocks [560,1592): zero borders of xt and y1t
// wdf: [((tap*4+kb)*2+nt)*64 + l]*8 + j  = w_c[oc][c][tap],
//      oc = nt*32 + (l&31), c = kb*16 + (l>>5)*8 + j
// wof: [(tap*4+kb)*64 + l]*8 + j,  ch = l&31 (27 padded to 32), same c
// ---------------------------------------------------------------------------
__global__ __launch_bounds__(256, 2) void prep(
    const float* __restrict__ x, ushort* __restrict__ xtt, ushort* __restrict__ y1t,
    const float* __restrict__ wc1, const float* __restrict__ wp1, const float* __restrict__ wm1,
    const float* __restrict__ wc2, const float* __restrict__ wp2, const float* __restrict__ wm2,
    ushort* __restrict__ wdf1, ushort* __restrict__ wof1,
    ushort* __restrict__ wdf2, ushort* __restrict__ wof2)
{
    int t = threadIdx.x;
    if (blockIdx.x < 432) {
        int idx0 = blockIdx.x * 256 + t;
        union { __hip_bfloat16 h; ushort u; } cv;
        if (idx0 < 73728) {
            int lay = idx0 >= 36864;
            int idx = idx0 - lay * 36864;
            const float* wc = lay ? wc2 : wc1;
            ushort* dst = lay ? wdf2 : wdf1;
            int j = idx & 7, l = (idx >> 3) & 63;
            int nt = (idx >> 9) & 1, kb = (idx >> 10) & 3, tap = idx >> 12;
            int oc = nt * 32 + (l & 31);
            int c  = kb * 16 + ((l >> 5) << 3) + j;
            cv.h = __float2bfloat16(wc[(oc * 64 + c) * 9 + tap]);
            dst[idx] = cv.u;
        } else if (idx0 < 110592) {
            int r = idx0 - 73728;
            int lay = r >= 18432;
            int idx = r - lay * 18432;
            const float* wp = lay ? wp2 : wp1;
            const float* wm = lay ? wm2 : wm1;
            ushort* dst = lay ? wof2 : wof1;
            int j = idx & 7, l = (idx >> 3) & 63;
            int kb = (idx >> 9) & 3, tap = idx >> 11;
            int ch = l & 31;
            int c  = kb * 16 + ((l >> 5) << 3) + j;
            float v = 0.f;
            if (ch < 18)      v = wp[(ch * 64 + c) * 9 + tap];
            else if (ch < 27) v = wm[((ch - 18) * 64 + c) * 9 + tap];
            cv.h = __float2bfloat16(v);
            dst[idx] = cv.u;
        }
        return;
    }
    int bx = blockIdx.x - 432;
    int l = t & 63, wv = t >> 6;
    if (bx < 128) {
        int c2 = l & 31, ps = l >> 5;
        int pix0w = bx * 512 + wv * 128;
        int bq = pix0w >> 14;
        const float* xp0 = x + ((size_t)(bq * 64 + c2 * 2)) * HWSZ;
        ushort* xw = xtt + (size_t)bq * SLAB;
        #pragma unroll 8
        for (int p = 0; p < 64; ++p) {
            int pxi = (pix0w + p * 2 + ps) & (HWSZ - 1);
            int i = pxi >> 7, j = pxi & 127;
            uint u = pk2bf(xp0[pxi], xp0[pxi + HWSZ]);
            *(uint*)(xw + ((i + 1) * PADW + (j + 1)) * 64 + c2 * 2) = u;
        }
    } else {
        int idx = (bx - 128) * 256 + t;
        if (idx >= 264192) return;
        ushort* buf = (idx >= 132096) ? y1t : xtt;
        int e_all = idx % 132096;
        int bq = e_all / 33024, e = e_all % 33024;
        int i, j, c;
        if (e < 8320)       { i = 0;   j = e >> 6; c = e & 63; }
        else if (e < 16640) { int e2 = e - 8320; i = 129; j = e2 >> 6; c = e2 & 63; }
        else                { int e2 = e - 16640; c = e2 & 63;
                              i = (e2 >> 7) + 1; j = ((e2 >> 6) & 1) ? 129 : 0; }
        buf[(size_t)bq * SLAB + (i * PADW + j) * 64 + c] = 0;
    }
}

// ---------------------------------------------------------------------------
// Fused layer, 32x32x16 MFMA. 256 thr / 4 waves; 8x16-px patch; wave wv owns
// rows {2wv, 2wv+1} x 16 cols = 32 px (M=32 of the MFMA).
//  stage: 15x23-cell window, 144B cell stride (bank-rotating, no XOR)
//  phase 1: offset/mask conv, 36 MFMA, N=32 -> omS LDS (wave-private)
//  phase 2: coords pass -> wave-uniform clean/dirty; clean: per tap 16
//           ds_read_b128 corners + 4 combines + 8 MFMA (N=64 as 2x32)
// Weight traffic per wave covers 32 px (2x better than 16x16 structure).
// ---------------------------------------------------------------------------
#define MF32(a,b,c) __builtin_amdgcn_mfma_f32_32x32x16_bf16(a,b,c,0,0,0)

__global__ __launch_bounds__(256, 2) void fused(
    const ushort* __restrict__ xt, const ushort* __restrict__ wof,
    const float* __restrict__ bp, const float* __restrict__ bm,
    const ushort* __restrict__ wdf, const float* __restrict__ xres,
    float* __restrict__ outn, ushort* __restrict__ y1t, int mode)
{
    __shared__ __align__(16) char sm[SM_BYTES];
    const int t = threadIdx.x, l = t & 63, wv = t >> 6;
    // XCD swizzle: 512 blocks, 64 contiguous per XCD
    const int lb = (blockIdx.x & 7) * 64 + (blockIdx.x >> 3);
    const int bb = lb >> 7;                  // batch (128 blocks each)
    const int patch = lb & 127;              // 16 row-groups x 8 col-groups
    const int i0 = (patch >> 3) * 8;
    const int j0 = (patch & 7) * 16;
    const int p  = l & 31;                   // lane's pixel (A-row / coords)
    const int h5 = l >> 5;                   // lane's k-half
    const ushort* xb = xt + (size_t)bb * SLAB;
    const char* xbb = (const char*)xb;

    // ---------- stage window ----------
    for (int s = t; s < NCELL * 8; s += 256) {
        int q = s & 7, cq = s >> 3;
        int c = cq % WC, r = cq / WC;
        int ip = min(max(i0 - 2 + r, 0), 129);
        int jp = min(max(j0 - 2 + c, 0), 129);
        uint4 v = *(const uint4*)(xbb + ((ip * PADW + jp) << 7) + (q << 4));
        *(uint4*)(sm + cq * CSTRIDE + (q << 4)) = v;
    }
    __syncthreads();

    // ---------- phase 1: offset/mask conv (N=32, 36 MFMA) ----------
    f32x16 oacc = {0.f,0.f,0.f,0.f,0.f,0.f,0.f,0.f,0.f,0.f,0.f,0.f,0.f,0.f,0.f,0.f};
    {
        const int rbase = 2 * wv + (p >> 4) + 2;
        const int cbase = (p & 15) + 2;
        #pragma unroll
        for (int tap = 0; tap < 9; ++tap) {
            int ti = tap / 3, tj = tap - ti * 3;
            const char* cell = sm + ((rbase + ti) * WC + cbase + tj) * CSTRIDE;
            #pragma unroll
            for (int kb = 0; kb < 4; ++kb) {
                short8 b = *(const short8*)(wof + ((tap * 4 + kb) * 64 + l) * 8);
                short8 a = *(const short8*)(cell + ((kb * 2 + h5) << 4));
                oacc = MF32(a, b, oacc);
            }
        }
    }
    float* omS = (float*)(sm + OMS_OFF) + wv * 891;   // [27][33] per wave
    {
        int ch = l & 31;
        if (ch < 27) {
            float bias = (ch < 18) ? bp[ch] : bm[ch - 18];
            #pragma unroll
            for (int reg = 0; reg < 16; ++reg) {
                int m = (reg & 3) + 8 * (reg >> 2) + 4 * h5;
                float v = oacc[reg] + bias;
                if (ch >= 18) v = 1.f / (1.f + __expf(-v));
                omS[ch * 33 + m] = v;
            }
        }
    }

    // ---------- phase 2: coords pass, then wave-uniform branch ----------
    f32x16 acc0 = {0.f,0.f,0.f,0.f,0.f,0.f,0.f,0.f,0.f,0.f,0.f,0.f,0.f,0.f,0.f,0.f};
    f32x16 acc1 = acc0;
    const int irow = i0 + 2 * wv + (p >> 4), jcol = j0 + (p & 15);
    uint cpack[9]; float4 gw[9];
    bool okall = true;
    #pragma unroll
    for (int n = 0; n < 9; ++n) {
        int4 cc; float4 g;
        coords_tap_lds(omS, p, irow, jcol, n, cc, g);
        int rlt = cc.x - (i0 - 2), clt = cc.y - (j0 - 2);
        int rrb = cc.z - (i0 - 2), crb = cc.w - (j0 - 2);
        okall = okall & ((uint)rlt < (uint)WR) & ((uint)rrb < (uint)WR) &
                        ((uint)clt < (uint)WC) & ((uint)crb < (uint)WC);
        cpack[n] = (uint)(rlt & 255) | ((uint)(clt & 255) << 8) |
                   ((uint)(rrb & 255) << 16) | ((uint)(crb & 255) << 24);
        gw[n] = g;
    }

    if (__all(okall)) {
        #pragma unroll
        for (int n = 0; n < 9; ++n) {
            uint cp_ = cpack[n];
            int rlt = cp_ & 255, clt = (cp_ >> 8) & 255;
            int rrb = (cp_ >> 16) & 255, crb = cp_ >> 24;
            const char* bLT = sm + (rlt * WC + clt) * CSTRIDE;
            const char* bRB = sm + (rrb * WC + crb) * CSTRIDE;
            const char* bLB = sm + (rlt * WC + crb) * CSTRIDE;
            const char* bRT = sm + (rrb * WC + clt) * CSTRIDE;
            float4 g = gw[n];
            const ushort* wb = wdf + (size_t)n * 4096 + l * 8;
            #pragma unroll
            for (int kb = 0; kb < 4; ++kb) {
                int qo = (kb * 2 + h5) << 4;
                short8 w0 = *(const short8*)(wb + (kb * 2 + 0) * 512);
                short8 w1 = *(const short8*)(wb + (kb * 2 + 1) * 512);
                short8 sLT = *(const short8*)(bLT + qo);
                short8 sRB = *(const short8*)(bRB + qo);
                short8 sLB = *(const short8*)(bLB + qo);
                short8 sRT = *(const short8*)(bRT + qo);
                short8 a = combine4(sLT, sRB, sLB, sRT, g.x, g.y, g.z, g.w);
                acc0 = MF32(a, w0, acc0);
                acc1 = MF32(a, w1, acc1);
            }
        }
    } else {
        // dirty path: exact per-tap fallback (rare)
        #pragma unroll
        for (int n = 0; n < 9; ++n) {
            int4 cc; float4 g;
            coords_tap_lds(omS, p, irow, jcol, n, cc, g);
            int rlt = cc.x - (i0 - 2), clt = cc.y - (j0 - 2);
            int rrb = cc.z - (i0 - 2), crb = cc.w - (j0 - 2);
            bool ok = ((uint)rlt < (uint)WR) & ((uint)rrb < (uint)WR) &
                      ((uint)clt < (uint)WC) & ((uint)crb < (uint)WC);
            const ushort* wb = wdf + (size_t)n * 4096 + l * 8;
            #pragma unroll
            for (int kb = 0; kb < 4; ++kb) {
                int qo = (kb * 2 + h5) << 4;
                short8 w0 = *(const short8*)(wb + (kb * 2 + 0) * 512);
                short8 w1 = *(const short8*)(wb + (kb * 2 + 1) * 512);
                short8 sLT, sRB, sLB, sRT;
                if (ok) {
                    sLT = *(const short8*)(sm + (rlt * WC + clt) * CSTRIDE + qo);
                    sRB = *(const short8*)(sm + (rrb * WC + crb) * CSTRIDE + qo);
                    sLB = *(const short8*)(sm + (rlt * WC + crb) * CSTRIDE + qo);
                    sRT = *(const short8*)(sm + (rrb * WC + clt) * CSTRIDE + qo);
                } else {
                    sLT = *(const short8*)(xbb + (((cc.x * PADW + cc.y) << 7) + qo));
                    sRB = *(const short8*)(xbb + (((cc.z * PADW + cc.w) << 7) + qo));
                    sLB = *(const short8*)(xbb + (((cc.x * PADW + cc.w) << 7) + qo));
                    sRT = *(const short8*)(xbb + (((cc.z * PADW + cc.y) << 7) + qo));
                }
                short8 a = combine4(sLT, sRB, sLB, sRT, g.x, g.y, g.z, g.w);
                acc0 = MF32(a, w0, acc0);
                acc1 = MF32(a, w1, acc1);
            }
        }
    }

    // ---------- epilogue ----------
    if (mode == 0) {
        #pragma unroll
        for (int nt = 0; nt < 2; ++nt) {
            int oc = nt * 32 + (l & 31);
            const f32x16& av = nt ? acc1 : acc0;
            #pragma unroll
            for (int qd = 0; qd < 4; ++qd) {
                int m0 = 8 * qd + 4 * h5;
                int lr = m0 >> 4, col0 = m0 & 15;
                size_t o = ((size_t)(bb * 64 + oc)) * HWSZ +
                           (i0 + 2 * wv + lr) * 128 + j0 + col0;
                float4 rsd = *(const float4*)(xres + o);
                float4 vv;
                vv.x = av[qd * 4 + 0] + rsd.x; vv.y = av[qd * 4 + 1] + rsd.y;
                vv.z = av[qd * 4 + 2] + rsd.z; vv.w = av[qd * 4 + 3] + rsd.w;
                *(float4*)(outn + o) = vv;
            }
        }
    } else {
        __syncthreads();
        float* T = (float*)sm;                   // [64 oc][129] overlays window
        #pragma unroll
        for (int nt = 0; nt < 2; ++nt) {
            int oc = nt * 32 + (l & 31);
            const f32x16& av = nt ? acc1 : acc0;
            #pragma unroll
            for (int reg = 0; reg < 16; ++reg) {
                int m = (reg & 3) + 8 * (reg >> 2) + 4 * h5;
                int plin = (2 * wv + (m >> 4)) * 16 + (m & 15);
                T[oc * 129 + plin] = fmaxf(av[reg], 0.f);
            }
        }
        __syncthreads();
        int plin = t >> 1, och = (t & 1) * 32;
        int prow = plin >> 4, pcol = plin & 15;
        ushort* dst = y1t + (size_t)bb * SLAB +
                      ((i0 + prow + 1) * PADW + (j0 + pcol + 1)) * 64 + och;
        uint w[16];
        #pragma unroll
        for (int k2 = 0; k2 < 16; ++k2)
            w[k2] = pk2bf(T[(och + k2 * 2) * 129 + plin],
                          T[(och + k2 * 2 + 1) * 129 + plin]);
        *(uint4*)dst        = make_uint4(w[0],  w[1],  w[2],  w[3]);
        *(uint4*)(dst + 8)  = make_uint4(w[4],  w[5],  w[6],  w[7]);
        *(uint4*)(dst + 16) = make_uint4(w[8],  w[9],  w[10], w[11]);
        *(uint4*)(dst + 24) = make_uint4(w[12], w[13], w[14], w[15]);
    }
}

// ---------------------------------------------------------------------------
extern "C" void kernel_launch(void* const* d_in, const int* in_sizes, int n_in,
                              void* d_out, int out_size, void* d_ws, size_t ws_size,
                              hipStream_t stream)
{
    const float* x      = (const float*)d_in[0];
    const float* d1_w_p = (const float*)d_in[1];
    const float* d1_b_p = (const float*)d_in[2];
    const float* d1_w_m = (const float*)d_in[3];
    const float* d1_b_m = (const float*)d_in[4];
    const float* d1_w_c = (const float*)d_in[5];
    const float* d2_w_p = (const float*)d_in[6];
    const float* d2_b_p = (const float*)d_in[7];
    const float* d2_w_m = (const float*)d_in[8];
    const float* d2_b_m = (const float*)d_in[9];
    const float* d2_w_c = (const float*)d_in[10];
    float* out = (float*)d_out;

    char* ws = (char*)d_ws;
    ushort* xtt  = (ushort*)(ws);               //  8,652,800 B padded NHWC bf16 x
    ushort* y1t  = (ushort*)(ws + 8652800);     //  8,652,800 B padded NHWC bf16 y1
    ushort* wdf1 = (ushort*)(ws + 17305600);
    ushort* wof1 = (ushort*)(ws + 17379328);
    ushort* wdf2 = (ushort*)(ws + 17416192);
    ushort* wof2 = (ushort*)(ws + 17489920);

    prep<<<1592, 256, 0, stream>>>(x, xtt, y1t,
                                   d1_w_c, d1_w_p, d1_w_m, d2_w_c, d2_w_p, d2_w_m,
                                   wdf1, wof1, wdf2, wof2);

    fused<<<512, 256, 0, stream>>>(xtt, wof1, d1_b_p, d1_b_m, wdf1,
                                   nullptr, nullptr, y1t, 1);
    fused<<<512, 256, 0, stream>>>(y1t, wof2, d2_b_p, d2_b_m, wdf2,
                                   x, out, nullptr, 0);
}